// Round 15
// baseline (251.552 us; speedup 1.0000x reference)
//
#include <hip/hip_runtime.h>
#include <hip/hip_bf16.h>

// Problem constants (from reference)
#define NN 2048
#define TT 64
#define EE 16384
#define BB 64
#define K0C 32
#define EMBC 128
#define K1C 64
#define K2C 64
#define KSZ 7
#define POOLK 4
#define BNEPS 1e-5f

typedef __attribute__((ext_vector_type(8))) short short8;     // 8 bf16 (4 VGPRs)
typedef __attribute__((ext_vector_type(16))) float floatx16;  // 32x32 MFMA C/D frag

// float -> bf16 bits, round-to-nearest-even
static __device__ __forceinline__ unsigned short f2bf(float f) {
    unsigned int u = __float_as_uint(f);
    u += 0x7fffu + ((u >> 16) & 1u);
    return (unsigned short)(u >> 16);
}
static __device__ __forceinline__ float bflo(unsigned int u) { return __uint_as_float(u << 16); }
static __device__ __forceinline__ float bfhi(unsigned int u) { return __uint_as_float(u & 0xffff0000u); }

static __device__ __forceinline__ void unpack8_add(uint4 r, float* acc) {
    acc[0] += bflo(r.x); acc[1] += bfhi(r.x);
    acc[2] += bflo(r.y); acc[3] += bfhi(r.y);
    acc[4] += bflo(r.z); acc[5] += bfhi(r.z);
    acc[6] += bflo(r.w); acc[7] += bfhi(r.w);
}
static __device__ __forceinline__ void unpack8_set(uint4 r, float* acc) {
    acc[0] = bflo(r.x); acc[1] = bfhi(r.x);
    acc[2] = bflo(r.y); acc[3] = bfhi(r.y);
    acc[4] = bflo(r.z); acc[5] = bfhi(r.z);
    acc[6] = bflo(r.w); acc[7] = bfhi(r.w);
}
static __device__ __forceinline__ uint4 pack8(const float* a) {
    uint4 r;
    r.x = (unsigned int)f2bf(a[0]) | ((unsigned int)f2bf(a[1]) << 16);
    r.y = (unsigned int)f2bf(a[2]) | ((unsigned int)f2bf(a[3]) << 16);
    r.z = (unsigned int)f2bf(a[4]) | ((unsigned int)f2bf(a[5]) << 16);
    r.w = (unsigned int)f2bf(a[6]) | ((unsigned int)f2bf(a[7]) << 16);
    return r;
}

// ---------------------------------------------------------------------------
// Fused pre-pass 1: count_deg (blocks 0..63) || prep_weights (blocks 64..367)
// ---------------------------------------------------------------------------
__global__ void pre1_kernel(const int* __restrict__ ei, int* __restrict__ deg,
                            const float* __restrict__ g1w, const float* __restrict__ g2w,
                            const float* __restrict__ c2w,
                            unsigned short* __restrict__ Wt1,
                            unsigned short* __restrict__ Wt2,
                            unsigned short* __restrict__ Bt) {
    int b = blockIdx.x;
    if (b < 64) {
        int e = b * 256 + threadIdx.x;                // e < 16384 always
        atomicAdd(&deg[ei[EE + e]], 1);               // dst = second row
        return;
    }
    int idx = (b - 64) * 256 + threadIdx.x;
    if (idx < 4096) {
        int d = idx >> 5, k = idx & 31;
        Wt1[idx] = f2bf(g1w[k * 128 + d]);
    } else if (idx < 20480) {
        int j = idx - 4096;
        int d = j >> 7, k = j & 127;
        Wt2[j] = f2bf(g2w[k * 128 + d]);
    } else if (idx < 77824) {
        int j = idx - 20480;
        int c = j / 896, k = j % 896;
        Bt[j] = f2bf(c2w[k * 64 + c]);
    }
}

// ---------------------------------------------------------------------------
// Fused pre-pass 2 (1 block): exclusive scan of deg -> row_start, + dinv.
// ---------------------------------------------------------------------------
__global__ void scan_dinv_kernel(const int* __restrict__ deg, int* __restrict__ row_start,
                                 float* __restrict__ dinv) {
    __shared__ int tsum[256];
    int tid = threadIdx.x;
    int loc[8];
    int s = 0;
#pragma unroll
    for (int i = 0; i < 8; ++i) { loc[i] = s; s += deg[tid * 8 + i]; }
    tsum[tid] = s;
    __syncthreads();
    for (int off = 1; off < 256; off <<= 1) {
        int v = (tid >= off) ? tsum[tid - off] : 0;
        __syncthreads();
        tsum[tid] += v;
        __syncthreads();
    }
    int base = (tid > 0) ? tsum[tid - 1] : 0;
#pragma unroll
    for (int i = 0; i < 8; ++i) {
        int n = tid * 8 + i;
        row_start[n] = base + loc[i];
        dinv[n] = rsqrtf((float)deg[n] + 1.0f);       // +1 self loop
    }
    if (tid == 255) row_start[NN] = tsum[255];
}

// ---------------------------------------------------------------------------
// Fused pre-pass 3: conv1+bn1+relu+dinv-prescale (blocks 0..16383) writing
// h0t (T,N,32) || fill_csr (blocks 16384..16447).
// ---------------------------------------------------------------------------
__global__ void pre3_kernel(const float* __restrict__ x, const float* __restrict__ w,
                            const float* __restrict__ g, const float* __restrict__ b,
                            const float* __restrict__ m, const float* __restrict__ v,
                            const float* __restrict__ dinv,
                            unsigned short* __restrict__ h0t,
                            const int* __restrict__ ei, const int* __restrict__ row_start,
                            int* __restrict__ cursor, int* __restrict__ csr_src) {
    int blk = blockIdx.x;
    if (blk >= 16384) {
        int e = (blk - 16384) * 256 + threadIdx.x;    // e < 16384 always
        int s = ei[e];
        int d = ei[EE + e];
        int pos = row_start[d] + atomicAdd(&cursor[d], 1);
        csr_src[pos] = s;
        return;
    }
    int idx = blk * 256 + threadIdx.x;                // (t*2048 + n)*32 + c
    int c = idx & 31;
    int n = (idx >> 5) & 2047;
    int t = idx >> 16;
    float acc = 0.f;
#pragma unroll
    for (int k = 0; k < KSZ; ++k) {
        int tt = t + k - 3;
        if (tt >= 0 && tt < TT) acc += x[n * TT + tt] * w[k * K0C + c];
    }
    float scale = g[c] * rsqrtf(v[c] + BNEPS);
    float val = (acc - m[c]) * scale + b[c];
    h0t[idx] = f2bf(dinv[n] * fmaxf(val, 0.f));       // pre-scaled for GCN agg
}

// Batch-4 double-buffered gather pipeline (r7 form; 32B/edge, for gcn2).
#define GCN_GATHER_LOOP(CIN)                                                     \
    int e = rs;                                                                  \
    int i0, i1, i2, i3, j0, j1, j2, j3;                                          \
    uint4 a0, a1, a2, a3, a4, a5, a6, a7;                                        \
    uint4 b0, b1, b2, b3, b4, b5, b6, b7;                                        \
    i0 = csr_src[min(e + 0, EE - 1)]; i1 = csr_src[min(e + 1, EE - 1)];          \
    i2 = csr_src[min(e + 2, EE - 1)]; i3 = csr_src[min(e + 3, EE - 1)];          \
    {   /* self loop (coefficient 1, norm folded) — hides index latency */       \
        const uint4* p = (const uint4*)(basep + (size_t)n * (CIN));              \
        uint4 r0 = p[0], r1 = p[1];                                              \
        unpack8_set(r0, acc); unpack8_set(r1, acc + 8);                          \
    }                                                                            \
    a0 = ((const uint4*)(basep + (size_t)i0 * (CIN)))[0];                        \
    a1 = ((const uint4*)(basep + (size_t)i0 * (CIN)))[1];                        \
    a2 = ((const uint4*)(basep + (size_t)i1 * (CIN)))[0];                        \
    a3 = ((const uint4*)(basep + (size_t)i1 * (CIN)))[1];                        \
    a4 = ((const uint4*)(basep + (size_t)i2 * (CIN)))[0];                        \
    a5 = ((const uint4*)(basep + (size_t)i2 * (CIN)))[1];                        \
    a6 = ((const uint4*)(basep + (size_t)i3 * (CIN)))[0];                        \
    a7 = ((const uint4*)(basep + (size_t)i3 * (CIN)))[1];                        \
    j0 = csr_src[min(e + 4, EE - 1)]; j1 = csr_src[min(e + 5, EE - 1)];          \
    j2 = csr_src[min(e + 6, EE - 1)]; j3 = csr_src[min(e + 7, EE - 1)];          \
    while (e < re) {                                                             \
        if (e + 4 < re) {                                                        \
            b0 = ((const uint4*)(basep + (size_t)j0 * (CIN)))[0];                \
            b1 = ((const uint4*)(basep + (size_t)j0 * (CIN)))[1];                \
            b2 = ((const uint4*)(basep + (size_t)j1 * (CIN)))[0];                \
            b3 = ((const uint4*)(basep + (size_t)j1 * (CIN)))[1];                \
            b4 = ((const uint4*)(basep + (size_t)j2 * (CIN)))[0];                \
            b5 = ((const uint4*)(basep + (size_t)j2 * (CIN)))[1];                \
            b6 = ((const uint4*)(basep + (size_t)j3 * (CIN)))[0];                \
            b7 = ((const uint4*)(basep + (size_t)j3 * (CIN)))[1];                \
        }                                                                        \
        i0 = csr_src[min(e + 8, EE - 1)];  i1 = csr_src[min(e + 9, EE - 1)];     \
        i2 = csr_src[min(e + 10, EE - 1)]; i3 = csr_src[min(e + 11, EE - 1)];    \
        unpack8_add(a0, acc); unpack8_add(a1, acc + 8);                          \
        if (e + 1 < re) { unpack8_add(a2, acc); unpack8_add(a3, acc + 8); }      \
        if (e + 2 < re) { unpack8_add(a4, acc); unpack8_add(a5, acc + 8); }      \
        if (e + 3 < re) { unpack8_add(a6, acc); unpack8_add(a7, acc + 8); }      \
        e += 4;                                                                  \
        if (e >= re) break;                                                      \
        if (e + 4 < re) {                                                        \
            a0 = ((const uint4*)(basep + (size_t)i0 * (CIN)))[0];                \
            a1 = ((const uint4*)(basep + (size_t)i0 * (CIN)))[1];                \
            a2 = ((const uint4*)(basep + (size_t)i1 * (CIN)))[0];                \
            a3 = ((const uint4*)(basep + (size_t)i1 * (CIN)))[1];                \
            a4 = ((const uint4*)(basep + (size_t)i2 * (CIN)))[0];                \
            a5 = ((const uint4*)(basep + (size_t)i2 * (CIN)))[1];                \
            a6 = ((const uint4*)(basep + (size_t)i3 * (CIN)))[0];                \
            a7 = ((const uint4*)(basep + (size_t)i3 * (CIN)))[1];                \
        }                                                                        \
        j0 = csr_src[min(e + 8, EE - 1)];  j1 = csr_src[min(e + 9, EE - 1)];     \
        j2 = csr_src[min(e + 10, EE - 1)]; j3 = csr_src[min(e + 11, EE - 1)];    \
        unpack8_add(b0, acc); unpack8_add(b1, acc + 8);                          \
        if (e + 1 < re) { unpack8_add(b2, acc); unpack8_add(b3, acc + 8); }      \
        if (e + 2 < re) { unpack8_add(b4, acc); unpack8_add(b5, acc + 8); }      \
        if (e + 3 < re) { unpack8_add(b6, acc); unpack8_add(b7, acc + 8); }      \
        e += 4;                                                                  \
    }

// ---------------------------------------------------------------------------
// GCN layer 1, t-sliced (r13): 2048 blocks, 64 dsts/block, 4 threads/dst,
// batch-4 dbuf pipeline. 8 waves/SIMD.
// ---------------------------------------------------------------------------
__global__ __launch_bounds__(256) void gcn1_t_kernel(
        const unsigned short* __restrict__ h0t, const unsigned short* __restrict__ Wt,
        const float* __restrict__ bias, unsigned short* __restrict__ h1t,
        const int* __restrict__ row_start, const int* __restrict__ csr_src,
        const float* __restrict__ dinv) {
    constexpr int STRIDE = 40;
    __shared__ __align__(16) unsigned short sAgg[64 * STRIDE];
    const int b = blockIdx.x;                 // 2048 blocks = 64 t x 32 groups
    const int xcd = b & 7;
    const int idx = b >> 3;                   // 0..255
    const int t = xcd * 8 + (idx >> 5);       // slice-major within XCD
    const int g = idx & 31;
    const int n0 = g * 64;
    const int tid = threadIdx.x;
    const int sub = tid >> 2;                 // dst 0..63
    const int part = tid & 3;                 // 8-channel part
    const int n = n0 + sub;

    const unsigned short* basep = h0t + (size_t)t * (NN * K0C) + part * 8;
    int rs = row_start[n], re = row_start[n + 1];
    float acc[8];
    {
        int e = rs;
        int i0, i1, i2, i3, j0, j1, j2, j3;
        uint4 a0, a1, a2, a3, b0, b1, b2, b3;
        i0 = csr_src[min(e + 0, EE - 1)]; i1 = csr_src[min(e + 1, EE - 1)];
        i2 = csr_src[min(e + 2, EE - 1)]; i3 = csr_src[min(e + 3, EE - 1)];
        {   // self loop (coefficient 1, norm folded) — hides index latency
            uint4 s = *(const uint4*)(basep + (size_t)n * K0C);
            unpack8_set(s, acc);
        }
        a0 = *(const uint4*)(basep + (size_t)i0 * K0C);
        a1 = *(const uint4*)(basep + (size_t)i1 * K0C);
        a2 = *(const uint4*)(basep + (size_t)i2 * K0C);
        a3 = *(const uint4*)(basep + (size_t)i3 * K0C);
        j0 = csr_src[min(e + 4, EE - 1)]; j1 = csr_src[min(e + 5, EE - 1)];
        j2 = csr_src[min(e + 6, EE - 1)]; j3 = csr_src[min(e + 7, EE - 1)];
        while (e < re) {
            if (e + 4 < re) {
                b0 = *(const uint4*)(basep + (size_t)j0 * K0C);
                b1 = *(const uint4*)(basep + (size_t)j1 * K0C);
                b2 = *(const uint4*)(basep + (size_t)j2 * K0C);
                b3 = *(const uint4*)(basep + (size_t)j3 * K0C);
            }
            i0 = csr_src[min(e + 8, EE - 1)];  i1 = csr_src[min(e + 9, EE - 1)];
            i2 = csr_src[min(e + 10, EE - 1)]; i3 = csr_src[min(e + 11, EE - 1)];
            unpack8_add(a0, acc);
            if (e + 1 < re) unpack8_add(a1, acc);
            if (e + 2 < re) unpack8_add(a2, acc);
            if (e + 3 < re) unpack8_add(a3, acc);
            e += 4;
            if (e >= re) break;
            if (e + 4 < re) {
                a0 = *(const uint4*)(basep + (size_t)i0 * K0C);
                a1 = *(const uint4*)(basep + (size_t)i1 * K0C);
                a2 = *(const uint4*)(basep + (size_t)i2 * K0C);
                a3 = *(const uint4*)(basep + (size_t)i3 * K0C);
            }
            j0 = csr_src[min(e + 8, EE - 1)];  j1 = csr_src[min(e + 9, EE - 1)];
            j2 = csr_src[min(e + 10, EE - 1)]; j3 = csr_src[min(e + 11, EE - 1)];
            unpack8_add(b0, acc);
            if (e + 1 < re) unpack8_add(b1, acc);
            if (e + 2 < re) unpack8_add(b2, acc);
            if (e + 3 < re) unpack8_add(b3, acc);
            e += 4;
        }
    }
    {   // final dinv[dst] scale
        float dv = dinv[n];
#pragma unroll
        for (int i = 0; i < 8; ++i) acc[i] *= dv;
    }
    *(uint4*)&sAgg[sub * STRIDE + part * 8] = pack8(acc);
    __syncthreads();

    // MFMA (64x32)@(32x128): wave = col tile, two 32-row halves
    const int wave = tid >> 6;
    const int lane = tid & 63;
    const int l31 = lane & 31;
    const int q = lane >> 5;
    floatx16 accv0 = (floatx16)0.f;
    floatx16 accv1 = (floatx16)0.f;
#pragma unroll
    for (int kk = 0; kk < 2; ++kk) {
        short8 a0 = *(const short8*)&sAgg[l31 * STRIDE + kk * 16 + q * 8];
        short8 a1 = *(const short8*)&sAgg[(32 + l31) * STRIDE + kk * 16 + q * 8];
        short8 bb = *(const short8*)(Wt + (size_t)(32 * wave + l31) * K0C + kk * 16 + q * 8);
        accv0 = __builtin_amdgcn_mfma_f32_32x32x16_bf16(a0, bb, accv0, 0, 0, 0);
        accv1 = __builtin_amdgcn_mfma_f32_32x32x16_bf16(a1, bb, accv1, 0, 0, 0);
    }
    // epilogue: h1t = dinv[row] * relu(acc + bias)  (pre-scaled for gcn2)
    unsigned short* orow = h1t + ((size_t)t * NN + n0) * EMBC;
    {
        int col = 32 * wave + l31;
        float bv = bias[col];
#pragma unroll
        for (int r = 0; r < 16; ++r) {
            int row = (r & 3) + 8 * (r >> 2) + 4 * q;
            float dv0 = dinv[n0 + row];
            float dv1 = dinv[n0 + 32 + row];
            orow[row * EMBC + col] = f2bf(dv0 * fmaxf(accv0[r] + bv, 0.f));
            orow[(32 + row) * EMBC + col] = f2bf(dv1 * fmaxf(accv1[r] + bv, 0.f));
        }
    }
}

// ---------------------------------------------------------------------------
// GCN layer 2, t-sliced (r7 verbatim): batch-4 gather, 4096 blocks.
// ---------------------------------------------------------------------------
__global__ __launch_bounds__(256) void gcn2_t_kernel(
        const unsigned short* __restrict__ h1t, const unsigned short* __restrict__ Wt,
        const float* __restrict__ bias, unsigned short* __restrict__ h2,
        const int* __restrict__ row_start, const int* __restrict__ csr_src,
        const float* __restrict__ dinv) {
    constexpr int STRIDE = 136;
    __shared__ __align__(16) unsigned short sAgg[32 * STRIDE];
    const int b = blockIdx.x;                 // 4096 blocks = 64 t x 64 groups
    const int xcd = b & 7;
    const int idx = b >> 3;                   // 0..511
    const int t = xcd * 8 + (idx >> 6);       // slice-major within XCD
    const int g = idx & 63;
    const int n0 = g * 32;
    const int tid = threadIdx.x;
    const int sub = tid >> 3;                 // dst 0..31
    const int part = tid & 7;                 // 16-channel part
    const int n = n0 + sub;

    const unsigned short* basep = h1t + (size_t)t * (NN * EMBC) + part * 16;
    int rs = row_start[n], re = row_start[n + 1];
    float acc[16];
    GCN_GATHER_LOOP(EMBC)
    {   // final dinv[dst] scale
        float dv = dinv[n];
#pragma unroll
        for (int i = 0; i < 16; ++i) acc[i] *= dv;
    }
    *(uint4*)&sAgg[sub * STRIDE + part * 16] = pack8(acc);
    *(uint4*)&sAgg[sub * STRIDE + part * 16 + 8] = pack8(acc + 8);
    __syncthreads();

    // dense transform MFMA (32x128)@(128x128): wave ct -> col tile 32ct
    const int wave = tid >> 6;
    const int lane = tid & 63;
    const int l31 = lane & 31;
    const int q = lane >> 5;
    floatx16 accv = (floatx16)0.f;
#pragma unroll
    for (int kk = 0; kk < 8; ++kk) {
        short8 a = *(const short8*)&sAgg[l31 * STRIDE + kk * 16 + q * 8];
        short8 bb = *(const short8*)(Wt + (size_t)(32 * wave + l31) * EMBC + kk * 16 + q * 8);
        accv = __builtin_amdgcn_mfma_f32_32x32x16_bf16(a, bb, accv, 0, 0, 0);
    }
    __syncthreads();                          // all sAgg reads done
    {
        int col = 32 * wave + l31;
        float bv = bias[col];
#pragma unroll
        for (int r = 0; r < 16; ++r) {
            int row = (r & 3) + 8 * (r >> 2) + 4 * q;
            sAgg[row * STRIDE + col] = f2bf(fmaxf(accv[r] + bv, 0.f));
        }
    }
    __syncthreads();
    // coalesced store: thread -> (node, 16-ch chunk), 32 B each
    {
        const uint4* sp = (const uint4*)&sAgg[(tid >> 3) * STRIDE + (tid & 7) * 16];
        uint4* dp = (uint4*)(h2 + ((size_t)(n0 + (tid >> 3)) * TT + t) * EMBC + (tid & 7) * 16);
        dp[0] = sp[0];
        dp[1] = sp[1];
    }
}

// ---------------------------------------------------------------------------
// conv2 (v15): 1 node/block, 2048 blocks, LDS = sA only (18.6KB). B-fragments
// are per-lane CONTIGUOUS 128B runs of the L2-resident 114KB Bt table ->
// loaded global->register, double-buffered across kw. ZERO barriers in the
// kw loop (v14's 12-barrier serialization was the 63us cost; MfmaUtil 8.5%,
// all pipes idle). Occupancy ~4 blocks/CU (VGPR-capped), no barrier drain.
// Epilogue: bn2 + pool4 + relu + graph-mean-pool atomicAdd into g1.
// ---------------------------------------------------------------------------
__global__ __launch_bounds__(256, 4) void conv2_mfma_kernel(
        const unsigned short* __restrict__ h2, const unsigned short* __restrict__ Bt,
        const float* __restrict__ g2, const float* __restrict__ b2,
        const float* __restrict__ m2, const float* __restrict__ v2,
        float* __restrict__ g1) {
    constexpr int STRIDE = 136;
    __shared__ __align__(16) unsigned short sA[70 * STRIDE];
    const int tid = threadIdx.x;

    // stage node rows (64 x 128 = 16KB, coalesced)
    const uint4* src = (const uint4*)(h2 + (size_t)blockIdx.x * (TT * EMBC));
#pragma unroll
    for (int it = 0; it < 4; ++it) {
        int idx = tid + it * 256;             // 0..1023 (uint4 units)
        int row = idx >> 4, col = (idx & 15) * 8;
        *(uint4*)&sA[row * STRIDE + col] = src[idx];
    }
    if (tid < 96) {                           // zero pad rows 64..69
        int row = 64 + tid / 16, col = (tid & 15) * 8;
        uint4 z; z.x = z.y = z.z = z.w = 0u;
        *(uint4*)&sA[row * STRIDE + col] = z;
    }
    __syncthreads();                          // the ONLY barrier

    const int wave = tid >> 6;
    const int lane = tid & 63;
    const int l31 = lane & 31;
    const int q = lane >> 5;
    const int rh = wave & 1;                  // row-half
    const int ct = wave >> 1;                 // col-tile

    // per-lane B base: row (32ct+l31) of Bt, 8B sub-offset by q
    const unsigned short* bp = Bt + (size_t)(32 * ct + l31) * 896 + q * 8;

    floatx16 acc = (floatx16)0.f;
    uint4 bc[8], bn[8];
#pragma unroll
    for (int kk = 0; kk < 8; ++kk) bc[kk] = *(const uint4*)(bp + kk * 16);

    for (int kw = 0; kw < 7; ++kw) {
        if (kw < 6) {
#pragma unroll
            for (int kk = 0; kk < 8; ++kk)
                bn[kk] = *(const uint4*)(bp + (kw + 1) * 128 + kk * 16);
        }
#pragma unroll
        for (int kk = 0; kk < 8; ++kk) {
            short8 a = *(const short8*)&sA[(32 * rh + l31 + kw) * STRIDE + kk * 16 + q * 8];
            union { uint4 u; short8 s8; } ub; ub.u = bc[kk];
            acc = __builtin_amdgcn_mfma_f32_32x32x16_bf16(a, ub.s8, acc, 0, 0, 0);
        }
#pragma unroll
        for (int kk = 0; kk < 8; ++kk) bc[kk] = bn[kk];
    }
    int n = blockIdx.x;
    float* gout = g1 + (size_t)(n >> 5) * (14 * K1C);
    {
        int col = 32 * ct + l31;
        float scale = g2[col] * rsqrtf(v2[col] + BNEPS);
        float mean = m2[col], beta = b2[col];
#pragma unroll
        for (int j = 0; j < 4; ++j) {
            int grp = 2 * j + q + 8 * rh;
            if (grp < 14) {
                float p = 0.25f * (acc[4 * j] + acc[4 * j + 1] + acc[4 * j + 2] + acc[4 * j + 3]);
                float val = (p - mean) * scale + beta;
                atomicAdd(&gout[grp * K1C + col], fmaxf(val, 0.f) * (1.f / 32.f));
            }
        }
    }
}

// ---------------------------------------------------------------------------
// Head: g1 (B,14,64) already pooled -> conv3 + bn3 + pool4 + relu + flatten +
// dense (wave-parallel, shfl-reduced) + log_softmax. One block/graph.
// ---------------------------------------------------------------------------
__global__ __launch_bounds__(256) void head_kernel(
        const float* __restrict__ g1, const float* __restrict__ w3,
        const float* __restrict__ g3, const float* __restrict__ b3,
        const float* __restrict__ m3, const float* __restrict__ v3,
        const float* __restrict__ dw, const float* __restrict__ db,
        float* __restrict__ out) {
    __shared__ float sg[14 * 64];
    __shared__ float sconv[8 * 64];
    __shared__ float sflat[128];
    __shared__ float slog[4];
    int b = blockIdx.x;
    int tid = threadIdx.x;
    for (int i = tid; i < 14 * 64; i += 256) sg[i] = g1[(size_t)b * (14 * 64) + i];
    __syncthreads();
    for (int i = tid; i < 8 * 64; i += 256) {
        int t = i >> 6, c = i & 63;
        float acc = 0.f;
        for (int k = 0; k < KSZ; ++k)
            for (int cin = 0; cin < 64; ++cin)
                acc += sg[(t + k) * 64 + cin] * w3[((size_t)(k * 64 + cin)) * 64 + c];
        sconv[i] = acc;
    }
    __syncthreads();
    for (int i = tid; i < 128; i += 256) {
        int j = i >> 6, c = i & 63;
        float p = 0.25f * (sconv[(4 * j + 0) * 64 + c] + sconv[(4 * j + 1) * 64 + c] +
                           sconv[(4 * j + 2) * 64 + c] + sconv[(4 * j + 3) * 64 + c]);
        float scale = g3[c] * rsqrtf(v3[c] + BNEPS);
        float val = (p - m3[c]) * scale + b3[c];
        sflat[i] = fmaxf(val, 0.f);
    }
    __syncthreads();
    {   // dense: wave o computes logit o via 64-lane reduce over 128 elems
        int o = tid >> 6;                     // 0..3
        int l = tid & 63;
        float partial = sflat[l] * dw[l * 4 + o] + sflat[64 + l] * dw[(64 + l) * 4 + o];
#pragma unroll
        for (int off = 32; off > 0; off >>= 1) partial += __shfl_down(partial, off);
        if (l == 0) slog[o] = partial + db[o];
    }
    __syncthreads();
    if (tid < 4) {
        float mx = fmaxf(fmaxf(slog[0], slog[1]), fmaxf(slog[2], slog[3]));
        float s = expf(slog[0] - mx) + expf(slog[1] - mx) +
                  expf(slog[2] - mx) + expf(slog[3] - mx);
        out[b * 4 + tid] = slog[tid] - mx - logf(s);
    }
}

// ---------------------------------------------------------------------------
extern "C" void kernel_launch(void* const* d_in, const int* in_sizes, int n_in,
                              void* d_out, int out_size, void* d_ws, size_t ws_size,
                              hipStream_t stream) {
    const float* x       = (const float*)d_in[0];
    const int*   ei      = (const int*)d_in[1];
    // d_in[2] = batch (arange//32, handled analytically)
    const float* conv1_w = (const float*)d_in[3];
    const float* bn1_g   = (const float*)d_in[4];
    const float* bn1_b   = (const float*)d_in[5];
    const float* bn1_m   = (const float*)d_in[6];
    const float* bn1_v   = (const float*)d_in[7];
    const float* gcn1_w  = (const float*)d_in[8];
    const float* gcn1_b  = (const float*)d_in[9];
    const float* gcn2_w  = (const float*)d_in[10];
    const float* gcn2_b  = (const float*)d_in[11];
    const float* conv2_w = (const float*)d_in[12];
    const float* bn2_g   = (const float*)d_in[13];
    const float* bn2_b   = (const float*)d_in[14];
    const float* bn2_m   = (const float*)d_in[15];
    const float* bn2_v   = (const float*)d_in[16];
    const float* conv3_w = (const float*)d_in[17];
    const float* bn3_g   = (const float*)d_in[18];
    const float* bn3_b   = (const float*)d_in[19];
    const float* bn3_m   = (const float*)d_in[20];
    const float* bn3_v   = (const float*)d_in[21];
    const float* dense_w = (const float*)d_in[22];
    const float* dense_b = (const float*)d_in[23];
    float* out = (float*)d_out;

    // Workspace layout (256B-aligned slots). counters+g1 contiguous -> 1 memset.
    char* ws = (char*)d_ws;
    size_t off = 0;
    auto alloc = [&](size_t bytes) { size_t o = off; off += (bytes + 255) & ~(size_t)255; return o; };
    size_t o_counters = alloc(2 * NN * sizeof(int));          // deg | cursor (zeroed)
    size_t o_g1       = alloc((size_t)BB * 14 * K1C * sizeof(float));  // zeroed
    size_t o_rowstart = alloc((NN + 1) * sizeof(int));
    size_t o_csrsrc   = alloc(EE * sizeof(int));
    size_t o_dinv     = alloc(NN * sizeof(float));
    size_t o_wt1      = alloc(4096 * sizeof(unsigned short));
    size_t o_wt2      = alloc(16384 * sizeof(unsigned short));
    size_t o_bt       = alloc(57344 * sizeof(unsigned short));
    size_t o_h0       = alloc((size_t)NN * TT * K0C * sizeof(unsigned short));   // h0t (T,N,32)
    size_t o_h1       = alloc((size_t)NN * TT * EMBC * sizeof(unsigned short));  // h1t (T,N,128)
    size_t o_h2       = alloc((size_t)NN * TT * EMBC * sizeof(unsigned short));  // h2 (N,T,128)
    (void)alloc(4096); // slack

    int*   deg_i    = (int*)(ws + o_counters);
    float* g1       = (float*)(ws + o_g1);
    int*   rowstart = (int*)(ws + o_rowstart);
    int*   csr_src  = (int*)(ws + o_csrsrc);
    float* dinv     = (float*)(ws + o_dinv);
    unsigned short* Wt1 = (unsigned short*)(ws + o_wt1);
    unsigned short* Wt2 = (unsigned short*)(ws + o_wt2);
    unsigned short* Bt  = (unsigned short*)(ws + o_bt);
    unsigned short* h0t = (unsigned short*)(ws + o_h0);
    unsigned short* h1t = (unsigned short*)(ws + o_h1);
    unsigned short* h2  = (unsigned short*)(ws + o_h2);
    int* cursor = deg_i + NN;

    // single memset covers deg + cursor + g1 (contiguous)
    hipMemsetAsync(deg_i, 0, 2 * NN * sizeof(int) + (size_t)BB * 14 * K1C * sizeof(float),
                   stream);

    pre1_kernel<<<368, 256, 0, stream>>>(ei, deg_i, gcn1_w, gcn2_w, conv2_w, Wt1, Wt2, Bt);
    scan_dinv_kernel<<<1, 256, 0, stream>>>(deg_i, rowstart, dinv);
    pre3_kernel<<<16448, 256, 0, stream>>>(x, conv1_w, bn1_g, bn1_b, bn1_m, bn1_v,
                                           dinv, h0t, ei, rowstart, cursor, csr_src);

    gcn1_t_kernel<<<64 * 32, 256, 0, stream>>>(h0t, Wt1, gcn1_b, h1t,
                                               rowstart, csr_src, dinv);
    gcn2_t_kernel<<<64 * 64, 256, 0, stream>>>(h1t, Wt2, gcn2_b, h2,
                                               rowstart, csr_src, dinv);

    conv2_mfma_kernel<<<NN, 256, 0, stream>>>(h2, Bt, bn2_g, bn2_b, bn2_m, bn2_v, g1);
    head_kernel<<<BB, 256, 0, stream>>>(g1, conv3_w, bn3_g, bn3_b, bn3_m, bn3_v,
                                        dense_w, dense_b, out);
}

// Round 16
// 218.779 us; speedup vs baseline: 1.1498x; 1.1498x over previous
//
#include <hip/hip_runtime.h>
#include <hip/hip_bf16.h>

// Problem constants (from reference)
#define NN 2048
#define TT 64
#define EE 16384
#define BB 64
#define K0C 32
#define EMBC 128
#define K1C 64
#define K2C 64
#define KSZ 7
#define POOLK 4
#define BNEPS 1e-5f

typedef __attribute__((ext_vector_type(8))) short short8;     // 8 bf16 (4 VGPRs)
typedef __attribute__((ext_vector_type(16))) float floatx16;  // 32x32 MFMA C/D frag

// float -> bf16 bits, round-to-nearest-even
static __device__ __forceinline__ unsigned short f2bf(float f) {
    unsigned int u = __float_as_uint(f);
    u += 0x7fffu + ((u >> 16) & 1u);
    return (unsigned short)(u >> 16);
}
static __device__ __forceinline__ float bflo(unsigned int u) { return __uint_as_float(u << 16); }
static __device__ __forceinline__ float bfhi(unsigned int u) { return __uint_as_float(u & 0xffff0000u); }

static __device__ __forceinline__ void unpack8_add(uint4 r, float* acc) {
    acc[0] += bflo(r.x); acc[1] += bfhi(r.x);
    acc[2] += bflo(r.y); acc[3] += bfhi(r.y);
    acc[4] += bflo(r.z); acc[5] += bfhi(r.z);
    acc[6] += bflo(r.w); acc[7] += bfhi(r.w);
}
static __device__ __forceinline__ void unpack8_set(uint4 r, float* acc) {
    acc[0] = bflo(r.x); acc[1] = bfhi(r.x);
    acc[2] = bflo(r.y); acc[3] = bfhi(r.y);
    acc[4] = bflo(r.z); acc[5] = bfhi(r.z);
    acc[6] = bflo(r.w); acc[7] = bfhi(r.w);
}
static __device__ __forceinline__ uint4 pack8(const float* a) {
    uint4 r;
    r.x = (unsigned int)f2bf(a[0]) | ((unsigned int)f2bf(a[1]) << 16);
    r.y = (unsigned int)f2bf(a[2]) | ((unsigned int)f2bf(a[3]) << 16);
    r.z = (unsigned int)f2bf(a[4]) | ((unsigned int)f2bf(a[5]) << 16);
    r.w = (unsigned int)f2bf(a[6]) | ((unsigned int)f2bf(a[7]) << 16);
    return r;
}

// ---------------------------------------------------------------------------
// Fused pre-pass 1: count_deg (blocks 0..63) || prep_weights (blocks 64..367).
// v16: Bt is emitted in FRAGMENT ORDER Bt2[ct][kw][kk][lane][8] so conv2's
// per-instruction B load is lane-contiguous 1KB (v15's row-scattered 32B
// requests hit the ~30 GB/s/CU request wall -> 58us).
// ---------------------------------------------------------------------------
__global__ void pre1_kernel(const int* __restrict__ ei, int* __restrict__ deg,
                            const float* __restrict__ g1w, const float* __restrict__ g2w,
                            const float* __restrict__ c2w,
                            unsigned short* __restrict__ Wt1,
                            unsigned short* __restrict__ Wt2,
                            unsigned short* __restrict__ Bt) {
    int b = blockIdx.x;
    if (b < 64) {
        int e = b * 256 + threadIdx.x;                // e < 16384 always
        atomicAdd(&deg[ei[EE + e]], 1);               // dst = second row
        return;
    }
    int idx = (b - 64) * 256 + threadIdx.x;
    if (idx < 4096) {
        int d = idx >> 5, k = idx & 31;
        Wt1[idx] = f2bf(g1w[k * 128 + d]);
    } else if (idx < 20480) {
        int j = idx - 4096;
        int d = j >> 7, k = j & 127;
        Wt2[j] = f2bf(g2w[k * 128 + d]);
    } else if (idx < 77824) {
        int j2 = idx - 20480;                 // 0..57343
        int chunk = j2 >> 9;                  // 0..111 = ct*56 + kw*8 + kk
        int within = j2 & 511;
        int ct = chunk / 56;
        int rem = chunk % 56;
        int kw = rem >> 3, kk = rem & 7;
        int lane = within >> 3, jj = within & 7;
        int c = 32 * ct + (lane & 31);
        int k = kw * 128 + kk * 16 + (lane >> 5) * 8 + jj;
        Bt[j2] = f2bf(c2w[k * 64 + c]);
    }
}

// ---------------------------------------------------------------------------
// Fused pre-pass 2 (1 block): exclusive scan of deg -> row_start, + dinv.
// ---------------------------------------------------------------------------
__global__ void scan_dinv_kernel(const int* __restrict__ deg, int* __restrict__ row_start,
                                 float* __restrict__ dinv) {
    __shared__ int tsum[256];
    int tid = threadIdx.x;
    int loc[8];
    int s = 0;
#pragma unroll
    for (int i = 0; i < 8; ++i) { loc[i] = s; s += deg[tid * 8 + i]; }
    tsum[tid] = s;
    __syncthreads();
    for (int off = 1; off < 256; off <<= 1) {
        int v = (tid >= off) ? tsum[tid - off] : 0;
        __syncthreads();
        tsum[tid] += v;
        __syncthreads();
    }
    int base = (tid > 0) ? tsum[tid - 1] : 0;
#pragma unroll
    for (int i = 0; i < 8; ++i) {
        int n = tid * 8 + i;
        row_start[n] = base + loc[i];
        dinv[n] = rsqrtf((float)deg[n] + 1.0f);       // +1 self loop
    }
    if (tid == 255) row_start[NN] = tsum[255];
}

// ---------------------------------------------------------------------------
// Fused pre-pass 3: conv1+bn1+relu+dinv-prescale (blocks 0..16383) writing
// h0t (T,N,32) || fill_csr (blocks 16384..16447).
// ---------------------------------------------------------------------------
__global__ void pre3_kernel(const float* __restrict__ x, const float* __restrict__ w,
                            const float* __restrict__ g, const float* __restrict__ b,
                            const float* __restrict__ m, const float* __restrict__ v,
                            const float* __restrict__ dinv,
                            unsigned short* __restrict__ h0t,
                            const int* __restrict__ ei, const int* __restrict__ row_start,
                            int* __restrict__ cursor, int* __restrict__ csr_src) {
    int blk = blockIdx.x;
    if (blk >= 16384) {
        int e = (blk - 16384) * 256 + threadIdx.x;    // e < 16384 always
        int s = ei[e];
        int d = ei[EE + e];
        int pos = row_start[d] + atomicAdd(&cursor[d], 1);
        csr_src[pos] = s;
        return;
    }
    int idx = blk * 256 + threadIdx.x;                // (t*2048 + n)*32 + c
    int c = idx & 31;
    int n = (idx >> 5) & 2047;
    int t = idx >> 16;
    float acc = 0.f;
#pragma unroll
    for (int k = 0; k < KSZ; ++k) {
        int tt = t + k - 3;
        if (tt >= 0 && tt < TT) acc += x[n * TT + tt] * w[k * K0C + c];
    }
    float scale = g[c] * rsqrtf(v[c] + BNEPS);
    float val = (acc - m[c]) * scale + b[c];
    h0t[idx] = f2bf(dinv[n] * fmaxf(val, 0.f));       // pre-scaled for GCN agg
}

// Batch-4 double-buffered gather pipeline (r7 form; 32B/edge, for gcn2).
#define GCN_GATHER_LOOP(CIN)                                                     \
    int e = rs;                                                                  \
    int i0, i1, i2, i3, j0, j1, j2, j3;                                          \
    uint4 a0, a1, a2, a3, a4, a5, a6, a7;                                        \
    uint4 b0, b1, b2, b3, b4, b5, b6, b7;                                        \
    i0 = csr_src[min(e + 0, EE - 1)]; i1 = csr_src[min(e + 1, EE - 1)];          \
    i2 = csr_src[min(e + 2, EE - 1)]; i3 = csr_src[min(e + 3, EE - 1)];          \
    {   /* self loop (coefficient 1, norm folded) — hides index latency */       \
        const uint4* p = (const uint4*)(basep + (size_t)n * (CIN));              \
        uint4 r0 = p[0], r1 = p[1];                                              \
        unpack8_set(r0, acc); unpack8_set(r1, acc + 8);                          \
    }                                                                            \
    a0 = ((const uint4*)(basep + (size_t)i0 * (CIN)))[0];                        \
    a1 = ((const uint4*)(basep + (size_t)i0 * (CIN)))[1];                        \
    a2 = ((const uint4*)(basep + (size_t)i1 * (CIN)))[0];                        \
    a3 = ((const uint4*)(basep + (size_t)i1 * (CIN)))[1];                        \
    a4 = ((const uint4*)(basep + (size_t)i2 * (CIN)))[0];                        \
    a5 = ((const uint4*)(basep + (size_t)i2 * (CIN)))[1];                        \
    a6 = ((const uint4*)(basep + (size_t)i3 * (CIN)))[0];                        \
    a7 = ((const uint4*)(basep + (size_t)i3 * (CIN)))[1];                        \
    j0 = csr_src[min(e + 4, EE - 1)]; j1 = csr_src[min(e + 5, EE - 1)];          \
    j2 = csr_src[min(e + 6, EE - 1)]; j3 = csr_src[min(e + 7, EE - 1)];          \
    while (e < re) {                                                             \
        if (e + 4 < re) {                                                        \
            b0 = ((const uint4*)(basep + (size_t)j0 * (CIN)))[0];                \
            b1 = ((const uint4*)(basep + (size_t)j0 * (CIN)))[1];                \
            b2 = ((const uint4*)(basep + (size_t)j1 * (CIN)))[0];                \
            b3 = ((const uint4*)(basep + (size_t)j1 * (CIN)))[1];                \
            b4 = ((const uint4*)(basep + (size_t)j2 * (CIN)))[0];                \
            b5 = ((const uint4*)(basep + (size_t)j2 * (CIN)))[1];                \
            b6 = ((const uint4*)(basep + (size_t)j3 * (CIN)))[0];                \
            b7 = ((const uint4*)(basep + (size_t)j3 * (CIN)))[1];                \
        }                                                                        \
        i0 = csr_src[min(e + 8, EE - 1)];  i1 = csr_src[min(e + 9, EE - 1)];     \
        i2 = csr_src[min(e + 10, EE - 1)]; i3 = csr_src[min(e + 11, EE - 1)];    \
        unpack8_add(a0, acc); unpack8_add(a1, acc + 8);                          \
        if (e + 1 < re) { unpack8_add(a2, acc); unpack8_add(a3, acc + 8); }      \
        if (e + 2 < re) { unpack8_add(a4, acc); unpack8_add(a5, acc + 8); }      \
        if (e + 3 < re) { unpack8_add(a6, acc); unpack8_add(a7, acc + 8); }      \
        e += 4;                                                                  \
        if (e >= re) break;                                                      \
        if (e + 4 < re) {                                                        \
            a0 = ((const uint4*)(basep + (size_t)i0 * (CIN)))[0];                \
            a1 = ((const uint4*)(basep + (size_t)i0 * (CIN)))[1];                \
            a2 = ((const uint4*)(basep + (size_t)i1 * (CIN)))[0];                \
            a3 = ((const uint4*)(basep + (size_t)i1 * (CIN)))[1];                \
            a4 = ((const uint4*)(basep + (size_t)i2 * (CIN)))[0];                \
            a5 = ((const uint4*)(basep + (size_t)i2 * (CIN)))[1];                \
            a6 = ((const uint4*)(basep + (size_t)i3 * (CIN)))[0];                \
            a7 = ((const uint4*)(basep + (size_t)i3 * (CIN)))[1];                \
        }                                                                        \
        j0 = csr_src[min(e + 8, EE - 1)];  j1 = csr_src[min(e + 9, EE - 1)];     \
        j2 = csr_src[min(e + 10, EE - 1)]; j3 = csr_src[min(e + 11, EE - 1)];    \
        unpack8_add(b0, acc); unpack8_add(b1, acc + 8);                          \
        if (e + 1 < re) { unpack8_add(b2, acc); unpack8_add(b3, acc + 8); }      \
        if (e + 2 < re) { unpack8_add(b4, acc); unpack8_add(b5, acc + 8); }      \
        if (e + 3 < re) { unpack8_add(b6, acc); unpack8_add(b7, acc + 8); }      \
        e += 4;                                                                  \
    }

// ---------------------------------------------------------------------------
// GCN layer 1, t-sliced (r13): 2048 blocks, 64 dsts/block, 4 threads/dst,
// batch-4 dbuf pipeline. 8 waves/SIMD.
// ---------------------------------------------------------------------------
__global__ __launch_bounds__(256) void gcn1_t_kernel(
        const unsigned short* __restrict__ h0t, const unsigned short* __restrict__ Wt,
        const float* __restrict__ bias, unsigned short* __restrict__ h1t,
        const int* __restrict__ row_start, const int* __restrict__ csr_src,
        const float* __restrict__ dinv) {
    constexpr int STRIDE = 40;
    __shared__ __align__(16) unsigned short sAgg[64 * STRIDE];
    const int b = blockIdx.x;                 // 2048 blocks = 64 t x 32 groups
    const int xcd = b & 7;
    const int idx = b >> 3;                   // 0..255
    const int t = xcd * 8 + (idx >> 5);       // slice-major within XCD
    const int g = idx & 31;
    const int n0 = g * 64;
    const int tid = threadIdx.x;
    const int sub = tid >> 2;                 // dst 0..63
    const int part = tid & 3;                 // 8-channel part
    const int n = n0 + sub;

    const unsigned short* basep = h0t + (size_t)t * (NN * K0C) + part * 8;
    int rs = row_start[n], re = row_start[n + 1];
    float acc[8];
    {
        int e = rs;
        int i0, i1, i2, i3, j0, j1, j2, j3;
        uint4 a0, a1, a2, a3, b0, b1, b2, b3;
        i0 = csr_src[min(e + 0, EE - 1)]; i1 = csr_src[min(e + 1, EE - 1)];
        i2 = csr_src[min(e + 2, EE - 1)]; i3 = csr_src[min(e + 3, EE - 1)];
        {   // self loop (coefficient 1, norm folded) — hides index latency
            uint4 s = *(const uint4*)(basep + (size_t)n * K0C);
            unpack8_set(s, acc);
        }
        a0 = *(const uint4*)(basep + (size_t)i0 * K0C);
        a1 = *(const uint4*)(basep + (size_t)i1 * K0C);
        a2 = *(const uint4*)(basep + (size_t)i2 * K0C);
        a3 = *(const uint4*)(basep + (size_t)i3 * K0C);
        j0 = csr_src[min(e + 4, EE - 1)]; j1 = csr_src[min(e + 5, EE - 1)];
        j2 = csr_src[min(e + 6, EE - 1)]; j3 = csr_src[min(e + 7, EE - 1)];
        while (e < re) {
            if (e + 4 < re) {
                b0 = *(const uint4*)(basep + (size_t)j0 * K0C);
                b1 = *(const uint4*)(basep + (size_t)j1 * K0C);
                b2 = *(const uint4*)(basep + (size_t)j2 * K0C);
                b3 = *(const uint4*)(basep + (size_t)j3 * K0C);
            }
            i0 = csr_src[min(e + 8, EE - 1)];  i1 = csr_src[min(e + 9, EE - 1)];
            i2 = csr_src[min(e + 10, EE - 1)]; i3 = csr_src[min(e + 11, EE - 1)];
            unpack8_add(a0, acc);
            if (e + 1 < re) unpack8_add(a1, acc);
            if (e + 2 < re) unpack8_add(a2, acc);
            if (e + 3 < re) unpack8_add(a3, acc);
            e += 4;
            if (e >= re) break;
            if (e + 4 < re) {
                a0 = *(const uint4*)(basep + (size_t)i0 * K0C);
                a1 = *(const uint4*)(basep + (size_t)i1 * K0C);
                a2 = *(const uint4*)(basep + (size_t)i2 * K0C);
                a3 = *(const uint4*)(basep + (size_t)i3 * K0C);
            }
            j0 = csr_src[min(e + 8, EE - 1)];  j1 = csr_src[min(e + 9, EE - 1)];
            j2 = csr_src[min(e + 10, EE - 1)]; j3 = csr_src[min(e + 11, EE - 1)];
            unpack8_add(b0, acc);
            if (e + 1 < re) unpack8_add(b1, acc);
            if (e + 2 < re) unpack8_add(b2, acc);
            if (e + 3 < re) unpack8_add(b3, acc);
            e += 4;
        }
    }
    {   // final dinv[dst] scale
        float dv = dinv[n];
#pragma unroll
        for (int i = 0; i < 8; ++i) acc[i] *= dv;
    }
    *(uint4*)&sAgg[sub * STRIDE + part * 8] = pack8(acc);
    __syncthreads();

    // MFMA (64x32)@(32x128): wave = col tile, two 32-row halves
    const int wave = tid >> 6;
    const int lane = tid & 63;
    const int l31 = lane & 31;
    const int q = lane >> 5;
    floatx16 accv0 = (floatx16)0.f;
    floatx16 accv1 = (floatx16)0.f;
#pragma unroll
    for (int kk = 0; kk < 2; ++kk) {
        short8 a0 = *(const short8*)&sAgg[l31 * STRIDE + kk * 16 + q * 8];
        short8 a1 = *(const short8*)&sAgg[(32 + l31) * STRIDE + kk * 16 + q * 8];
        short8 bb = *(const short8*)(Wt + (size_t)(32 * wave + l31) * K0C + kk * 16 + q * 8);
        accv0 = __builtin_amdgcn_mfma_f32_32x32x16_bf16(a0, bb, accv0, 0, 0, 0);
        accv1 = __builtin_amdgcn_mfma_f32_32x32x16_bf16(a1, bb, accv1, 0, 0, 0);
    }
    // epilogue: h1t = dinv[row] * relu(acc + bias)  (pre-scaled for gcn2)
    unsigned short* orow = h1t + ((size_t)t * NN + n0) * EMBC;
    {
        int col = 32 * wave + l31;
        float bv = bias[col];
#pragma unroll
        for (int r = 0; r < 16; ++r) {
            int row = (r & 3) + 8 * (r >> 2) + 4 * q;
            float dv0 = dinv[n0 + row];
            float dv1 = dinv[n0 + 32 + row];
            orow[row * EMBC + col] = f2bf(dv0 * fmaxf(accv0[r] + bv, 0.f));
            orow[(32 + row) * EMBC + col] = f2bf(dv1 * fmaxf(accv1[r] + bv, 0.f));
        }
    }
}

// ---------------------------------------------------------------------------
// GCN layer 2, t-sliced (r7 verbatim): batch-4 gather, 4096 blocks.
// ---------------------------------------------------------------------------
__global__ __launch_bounds__(256) void gcn2_t_kernel(
        const unsigned short* __restrict__ h1t, const unsigned short* __restrict__ Wt,
        const float* __restrict__ bias, unsigned short* __restrict__ h2,
        const int* __restrict__ row_start, const int* __restrict__ csr_src,
        const float* __restrict__ dinv) {
    constexpr int STRIDE = 136;
    __shared__ __align__(16) unsigned short sAgg[32 * STRIDE];
    const int b = blockIdx.x;                 // 4096 blocks = 64 t x 64 groups
    const int xcd = b & 7;
    const int idx = b >> 3;                   // 0..511
    const int t = xcd * 8 + (idx >> 6);       // slice-major within XCD
    const int g = idx & 63;
    const int n0 = g * 32;
    const int tid = threadIdx.x;
    const int sub = tid >> 3;                 // dst 0..31
    const int part = tid & 7;                 // 16-channel part
    const int n = n0 + sub;

    const unsigned short* basep = h1t + (size_t)t * (NN * EMBC) + part * 16;
    int rs = row_start[n], re = row_start[n + 1];
    float acc[16];
    GCN_GATHER_LOOP(EMBC)
    {   // final dinv[dst] scale
        float dv = dinv[n];
#pragma unroll
        for (int i = 0; i < 16; ++i) acc[i] *= dv;
    }
    *(uint4*)&sAgg[sub * STRIDE + part * 16] = pack8(acc);
    *(uint4*)&sAgg[sub * STRIDE + part * 16 + 8] = pack8(acc + 8);
    __syncthreads();

    // dense transform MFMA (32x128)@(128x128): wave ct -> col tile 32ct
    const int wave = tid >> 6;
    const int lane = tid & 63;
    const int l31 = lane & 31;
    const int q = lane >> 5;
    floatx16 accv = (floatx16)0.f;
#pragma unroll
    for (int kk = 0; kk < 8; ++kk) {
        short8 a = *(const short8*)&sAgg[l31 * STRIDE + kk * 16 + q * 8];
        short8 bb = *(const short8*)(Wt + (size_t)(32 * wave + l31) * EMBC + kk * 16 + q * 8);
        accv = __builtin_amdgcn_mfma_f32_32x32x16_bf16(a, bb, accv, 0, 0, 0);
    }
    __syncthreads();                          // all sAgg reads done
    {
        int col = 32 * wave + l31;
        float bv = bias[col];
#pragma unroll
        for (int r = 0; r < 16; ++r) {
            int row = (r & 3) + 8 * (r >> 2) + 4 * q;
            sAgg[row * STRIDE + col] = f2bf(fmaxf(accv[r] + bv, 0.f));
        }
    }
    __syncthreads();
    // coalesced store: thread -> (node, 16-ch chunk), 32 B each
    {
        const uint4* sp = (const uint4*)&sAgg[(tid >> 3) * STRIDE + (tid & 7) * 16];
        uint4* dp = (uint4*)(h2 + ((size_t)(n0 + (tid >> 3)) * TT + t) * EMBC + (tid & 7) * 16);
        dp[0] = sp[0];
        dp[1] = sp[1];
    }
}

// ---------------------------------------------------------------------------
// conv2 (v16): 1 node/block, LDS = sA only, ZERO kw-loop barriers (v15), and
// B in FRAGMENT-ORDER layout Bt2[ct][kw][kk][lane][8]: each B-frag load is
// lane-contiguous 1KB per wave-instruction (v15's 32-row scatter was the
// request-throughput wall at 58us). Double-buffered B regs across kw.
// Epilogue: bn2 + pool4 + relu + graph-mean-pool atomicAdd into g1.
// ---------------------------------------------------------------------------
__global__ __launch_bounds__(256, 4) void conv2_mfma_kernel(
        const unsigned short* __restrict__ h2, const unsigned short* __restrict__ Bt,
        const float* __restrict__ g2, const float* __restrict__ b2,
        const float* __restrict__ m2, const float* __restrict__ v2,
        float* __restrict__ g1) {
    constexpr int STRIDE = 136;
    __shared__ __align__(16) unsigned short sA[70 * STRIDE];
    const int tid = threadIdx.x;

    // stage node rows (64 x 128 = 16KB, coalesced)
    const uint4* src = (const uint4*)(h2 + (size_t)blockIdx.x * (TT * EMBC));
#pragma unroll
    for (int it = 0; it < 4; ++it) {
        int idx = tid + it * 256;             // 0..1023 (uint4 units)
        int row = idx >> 4, col = (idx & 15) * 8;
        *(uint4*)&sA[row * STRIDE + col] = src[idx];
    }
    if (tid < 96) {                           // zero pad rows 64..69
        int row = 64 + tid / 16, col = (tid & 15) * 8;
        uint4 z; z.x = z.y = z.z = z.w = 0u;
        *(uint4*)&sA[row * STRIDE + col] = z;
    }
    __syncthreads();                          // the ONLY barrier

    const int wave = tid >> 6;
    const int lane = tid & 63;
    const int l31 = lane & 31;
    const int q = lane >> 5;
    const int rh = wave & 1;                  // row-half
    const int ct = wave >> 1;                 // col-tile

    // fragment-order B: Bt2 + ct*28672 + (kw*8+kk)*512 + lane*8 (u16 units)
    const unsigned short* bp = Bt + ct * 28672 + lane * 8;

    floatx16 acc = (floatx16)0.f;
    uint4 bc[8], bn[8];
#pragma unroll
    for (int kk = 0; kk < 8; ++kk) bc[kk] = *(const uint4*)(bp + kk * 512);

    for (int kw = 0; kw < 7; ++kw) {
        if (kw < 6) {
#pragma unroll
            for (int kk = 0; kk < 8; ++kk)
                bn[kk] = *(const uint4*)(bp + ((kw + 1) * 8 + kk) * 512);
        }
#pragma unroll
        for (int kk = 0; kk < 8; ++kk) {
            short8 a = *(const short8*)&sA[(32 * rh + l31 + kw) * STRIDE + kk * 16 + q * 8];
            union { uint4 u; short8 s8; } ub; ub.u = bc[kk];
            acc = __builtin_amdgcn_mfma_f32_32x32x16_bf16(a, ub.s8, acc, 0, 0, 0);
        }
#pragma unroll
        for (int kk = 0; kk < 8; ++kk) bc[kk] = bn[kk];
    }
    int n = blockIdx.x;
    float* gout = g1 + (size_t)(n >> 5) * (14 * K1C);
    {
        int col = 32 * ct + l31;
        float scale = g2[col] * rsqrtf(v2[col] + BNEPS);
        float mean = m2[col], beta = b2[col];
#pragma unroll
        for (int j = 0; j < 4; ++j) {
            int grp = 2 * j + q + 8 * rh;
            if (grp < 14) {
                float p = 0.25f * (acc[4 * j] + acc[4 * j + 1] + acc[4 * j + 2] + acc[4 * j + 3]);
                float val = (p - mean) * scale + beta;
                atomicAdd(&gout[grp * K1C + col], fmaxf(val, 0.f) * (1.f / 32.f));
            }
        }
    }
}

// ---------------------------------------------------------------------------
// Head: g1 (B,14,64) already pooled -> conv3 + bn3 + pool4 + relu + flatten +
// dense (wave-parallel, shfl-reduced) + log_softmax. One block/graph.
// ---------------------------------------------------------------------------
__global__ __launch_bounds__(256) void head_kernel(
        const float* __restrict__ g1, const float* __restrict__ w3,
        const float* __restrict__ g3, const float* __restrict__ b3,
        const float* __restrict__ m3, const float* __restrict__ v3,
        const float* __restrict__ dw, const float* __restrict__ db,
        float* __restrict__ out) {
    __shared__ float sg[14 * 64];
    __shared__ float sconv[8 * 64];
    __shared__ float sflat[128];
    __shared__ float slog[4];
    int b = blockIdx.x;
    int tid = threadIdx.x;
    for (int i = tid; i < 14 * 64; i += 256) sg[i] = g1[(size_t)b * (14 * 64) + i];
    __syncthreads();
    for (int i = tid; i < 8 * 64; i += 256) {
        int t = i >> 6, c = i & 63;
        float acc = 0.f;
        for (int k = 0; k < KSZ; ++k)
            for (int cin = 0; cin < 64; ++cin)
                acc += sg[(t + k) * 64 + cin] * w3[((size_t)(k * 64 + cin)) * 64 + c];
        sconv[i] = acc;
    }
    __syncthreads();
    for (int i = tid; i < 128; i += 256) {
        int j = i >> 6, c = i & 63;
        float p = 0.25f * (sconv[(4 * j + 0) * 64 + c] + sconv[(4 * j + 1) * 64 + c] +
                           sconv[(4 * j + 2) * 64 + c] + sconv[(4 * j + 3) * 64 + c]);
        float scale = g3[c] * rsqrtf(v3[c] + BNEPS);
        float val = (p - m3[c]) * scale + b3[c];
        sflat[i] = fmaxf(val, 0.f);
    }
    __syncthreads();
    {   // dense: wave o computes logit o via 64-lane reduce over 128 elems
        int o = tid >> 6;                     // 0..3
        int l = tid & 63;
        float partial = sflat[l] * dw[l * 4 + o] + sflat[64 + l] * dw[(64 + l) * 4 + o];
#pragma unroll
        for (int off = 32; off > 0; off >>= 1) partial += __shfl_down(partial, off);
        if (l == 0) slog[o] = partial + db[o];
    }
    __syncthreads();
    if (tid < 4) {
        float mx = fmaxf(fmaxf(slog[0], slog[1]), fmaxf(slog[2], slog[3]));
        float s = expf(slog[0] - mx) + expf(slog[1] - mx) +
                  expf(slog[2] - mx) + expf(slog[3] - mx);
        out[b * 4 + tid] = slog[tid] - mx - logf(s);
    }
}

// ---------------------------------------------------------------------------
extern "C" void kernel_launch(void* const* d_in, const int* in_sizes, int n_in,
                              void* d_out, int out_size, void* d_ws, size_t ws_size,
                              hipStream_t stream) {
    const float* x       = (const float*)d_in[0];
    const int*   ei      = (const int*)d_in[1];
    // d_in[2] = batch (arange//32, handled analytically)
    const float* conv1_w = (const float*)d_in[3];
    const float* bn1_g   = (const float*)d_in[4];
    const float* bn1_b   = (const float*)d_in[5];
    const float* bn1_m   = (const float*)d_in[6];
    const float* bn1_v   = (const float*)d_in[7];
    const float* gcn1_w  = (const float*)d_in[8];
    const float* gcn1_b  = (const float*)d_in[9];
    const float* gcn2_w  = (const float*)d_in[10];
    const float* gcn2_b  = (const float*)d_in[11];
    const float* conv2_w = (const float*)d_in[12];
    const float* bn2_g   = (const float*)d_in[13];
    const float* bn2_b   = (const float*)d_in[14];
    const float* bn2_m   = (const float*)d_in[15];
    const float* bn2_v   = (const float*)d_in[16];
    const float* conv3_w = (const float*)d_in[17];
    const float* bn3_g   = (const float*)d_in[18];
    const float* bn3_b   = (const float*)d_in[19];
    const float* bn3_m   = (const float*)d_in[20];
    const float* bn3_v   = (const float*)d_in[21];
    const float* dense_w = (const float*)d_in[22];
    const float* dense_b = (const float*)d_in[23];
    float* out = (float*)d_out;

    // Workspace layout (256B-aligned slots). counters+g1 contiguous -> 1 memset.
    char* ws = (char*)d_ws;
    size_t off = 0;
    auto alloc = [&](size_t bytes) { size_t o = off; off += (bytes + 255) & ~(size_t)255; return o; };
    size_t o_counters = alloc(2 * NN * sizeof(int));          // deg | cursor (zeroed)
    size_t o_g1       = alloc((size_t)BB * 14 * K1C * sizeof(float));  // zeroed
    size_t o_rowstart = alloc((NN + 1) * sizeof(int));
    size_t o_csrsrc   = alloc(EE * sizeof(int));
    size_t o_dinv     = alloc(NN * sizeof(float));
    size_t o_wt1      = alloc(4096 * sizeof(unsigned short));
    size_t o_wt2      = alloc(16384 * sizeof(unsigned short));
    size_t o_bt       = alloc(57344 * sizeof(unsigned short));
    size_t o_h0       = alloc((size_t)NN * TT * K0C * sizeof(unsigned short));   // h0t (T,N,32)
    size_t o_h1       = alloc((size_t)NN * TT * EMBC * sizeof(unsigned short));  // h1t (T,N,128)
    size_t o_h2       = alloc((size_t)NN * TT * EMBC * sizeof(unsigned short));  // h2 (N,T,128)
    (void)alloc(4096); // slack

    int*   deg_i    = (int*)(ws + o_counters);
    float* g1       = (float*)(ws + o_g1);
    int*   rowstart = (int*)(ws + o_rowstart);
    int*   csr_src  = (int*)(ws + o_csrsrc);
    float* dinv     = (float*)(ws + o_dinv);
    unsigned short* Wt1 = (unsigned short*)(ws + o_wt1);
    unsigned short* Wt2 = (unsigned short*)(ws + o_wt2);
    unsigned short* Bt  = (unsigned short*)(ws + o_bt);
    unsigned short* h0t = (unsigned short*)(ws + o_h0);
    unsigned short* h1t = (unsigned short*)(ws + o_h1);
    unsigned short* h2  = (unsigned short*)(ws + o_h2);
    int* cursor = deg_i + NN;

    // single memset covers deg + cursor + g1 (contiguous)
    hipMemsetAsync(deg_i, 0, 2 * NN * sizeof(int) + (size_t)BB * 14 * K1C * sizeof(float),
                   stream);

    pre1_kernel<<<368, 256, 0, stream>>>(ei, deg_i, gcn1_w, gcn2_w, conv2_w, Wt1, Wt2, Bt);
    scan_dinv_kernel<<<1, 256, 0, stream>>>(deg_i, rowstart, dinv);
    pre3_kernel<<<16448, 256, 0, stream>>>(x, conv1_w, bn1_g, bn1_b, bn1_m, bn1_v,
                                           dinv, h0t, ei, rowstart, cursor, csr_src);

    gcn1_t_kernel<<<64 * 32, 256, 0, stream>>>(h0t, Wt1, gcn1_b, h1t,
                                               rowstart, csr_src, dinv);
    gcn2_t_kernel<<<64 * 64, 256, 0, stream>>>(h1t, Wt2, gcn2_b, h2,
                                               rowstart, csr_src, dinv);

    conv2_mfma_kernel<<<NN, 256, 0, stream>>>(h2, Bt, bn2_g, bn2_b, bn2_m, bn2_v, g1);
    head_kernel<<<BB, 256, 0, stream>>>(g1, conv3_w, bn3_g, bn3_b, bn3_m, bn3_v,
                                        dense_w, dense_b, out);
}